// Round 6
// baseline (63.146 us; speedup 1.0000x reference)
//
#include <hip/hip_runtime.h>
#include <hip/hip_bf16.h>

// (B, S, NK, H, D, DM) = (2, 2048, 32, 8, 64, 512)
constexpr int Bb  = 2;
constexpr int Ss  = 2048;
constexpr int NKk = 32;
constexpr int Hh  = 8;
constexpr int DMm = 512;
constexpr int Mm  = Bb * Ss;   // 4096 rows
constexpr int QKV = 1536;      // concat row stride

typedef __attribute__((ext_vector_type(8))) short bf16x8;
typedef __attribute__((ext_vector_type(4))) float f32x4;

__device__ __forceinline__ float b2f(unsigned short u) {
  return __uint_as_float((unsigned)u << 16);
}
__device__ __forceinline__ unsigned short f2b(float f) {
  unsigned u = __float_as_uint(f);
  unsigned r = (u + 0x7fffu + ((u >> 16) & 1u)) >> 16;   // RNE
  return (unsigned short)r;
}
__device__ __forceinline__ void gload_lds16(const ushort* g, ushort* l) {
  __builtin_amdgcn_global_load_lds(
      (const __attribute__((address_space(1))) void*)g,
      (__attribute__((address_space(3))) void*)l, 16, 0, 0);
}

// ---------------------------------------------------------------------------
// Merged conversion kernel. grid (8,8,8), 256 threads.
//  z<4 : weight transpose+convert, W fp32 [k][n] (512x512) -> Wt bf16 [n][k]
//  z>=4: hs fp32 -> Xb bf16 flat
// ---------------------------------------------------------------------------
__global__ __launch_bounds__(256) void cvt_all_k(
    const float* __restrict__ hs,
    const float* __restrict__ Wq, const float* __restrict__ Wk,
    const float* __restrict__ Wv, const float* __restrict__ Wf,
    ushort* __restrict__ Xb, ushort* __restrict__ Wt3, ushort* __restrict__ Wtf)
{
  __shared__ float tile[64][65];
  const int z = blockIdx.z;
  const int t = threadIdx.x;

  if (z >= 4) {
    const int cid = (z - 4) * 64 + blockIdx.x * 8 + blockIdx.y;   // 0..255
    const size_t base8 = (size_t)cid * 1024;                      // uint4 units
#pragma unroll
    for (int it = 0; it < 4; ++it) {
      const size_t i = base8 + it * 256 + t;
      const float4 a = reinterpret_cast<const float4*>(hs)[2 * i];
      const float4 b = reinterpret_cast<const float4*>(hs)[2 * i + 1];
      ushort o[8] = {f2b(a.x), f2b(a.y), f2b(a.z), f2b(a.w),
                     f2b(b.x), f2b(b.y), f2b(b.z), f2b(b.w)};
      reinterpret_cast<uint4*>(Xb)[i] = *reinterpret_cast<uint4*>(o);
    }
    return;
  }

  const float* W = (z == 0) ? Wq : (z == 1) ? Wk : (z == 2) ? Wv : Wf;
  ushort* Wt = (z < 3) ? (Wt3 + (size_t)z * 512 * 512) : Wtf;

  const int k0 = blockIdx.x * 64, n0 = blockIdx.y * 64;
#pragma unroll
  for (int p = 0; p < 4; ++p) {
    const int r = (t >> 4) + p * 16, c = (t & 15) * 4;
    const float4 v = *reinterpret_cast<const float4*>(&W[(size_t)(k0 + r) * 512 + n0 + c]);
    tile[r][c] = v.x; tile[r][c + 1] = v.y; tile[r][c + 2] = v.z; tile[r][c + 3] = v.w;
  }
  __syncthreads();
  const int n = t >> 2, ks = (t & 3) * 16;
  ushort o[16];
#pragma unroll
  for (int i = 0; i < 16; ++i) o[i] = f2b(tile[ks + i][n]);
  *reinterpret_cast<uint4*>(&Wt[(size_t)(n0 + n) * 512 + k0 + ks])     = *reinterpret_cast<uint4*>(&o[0]);
  *reinterpret_cast<uint4*>(&Wt[(size_t)(n0 + n) * 512 + k0 + ks + 8]) = *reinterpret_cast<uint4*>(&o[8]);
}

// ---------------------------------------------------------------------------
// 2-phase double-buffered bf16 MFMA GEMM. Y = Xb @ Wt^T.
// BM=BMv, BN=BNv, BK=64. 4 waves (2x2); wave tile (BMv/2) x (BNv/2).
// Staging: global_load_lds w=16, SOURCE-swizzled 16B blocks; reads same XOR.
// ---------------------------------------------------------------------------
template <int OUT_BF16, int BMv, int BNv>
__global__ __launch_bounds__(256) void gemm_dbuf(
    const ushort* __restrict__ Xb, const ushort* __restrict__ Wt,
    void* __restrict__ Yv, const float* __restrict__ bias,
    const float* __restrict__ resid, int ldY)
{
  constexpr int MI = BMv / 32;                    // A-frags per wave
  constexpr int NJ = BNv / 32;                    // B-frags per wave
  constexpr int ASZ = BMv * 64;                   // ushorts per A buffer
  __shared__ ushort smem[2 * ASZ + 2 * BNv * 64];

  const int bm = blockIdx.x * BMv;
  const int bn = blockIdx.y * BNv;
  const int t  = threadIdx.x;
  const int wave = t >> 6, lane = t & 63;
  const int wm = (wave >> 1) * (BMv / 2);
  const int wn = (wave & 1) * (BNv / 2);

  f32x4 acc[MI][NJ] = {};

  auto stage = [&](int buf, int k0) {
    ushort* A = smem + buf * ASZ;
    ushort* B = smem + 2 * ASZ + buf * (BNv * 64);
#pragma unroll
    for (int p = 0; p < MI; ++p) {                // A: BMv x 64 bf16
      const int i = p * 256 + t;
      const int row = i >> 3, sb = i & 7;
      gload_lds16(Xb + (size_t)(bm + row) * 512 + k0 + ((sb ^ (row & 7)) << 3),
                  &A[(size_t)(p * 256 + wave * 64) * 8]);
    }
#pragma unroll
    for (int p = 0; p < NJ; ++p) {                // B: BNv x 64 bf16
      const int i = p * 256 + t;
      const int row = i >> 3, sb = i & 7;
      gload_lds16(Wt + (size_t)(bn + row) * 512 + k0 + ((sb ^ (row & 7)) << 3),
                  &B[(size_t)(p * 256 + wave * 64) * 8]);
    }
  };

  auto compute = [&](int buf) {
    const ushort* A = smem + buf * ASZ;
    const ushort* B = smem + 2 * ASZ + buf * (BNv * 64);
#pragma unroll
    for (int ks = 0; ks < 2; ++ks) {
      const int kb = ks * 4 + (lane >> 4);
      bf16x8 af[MI], bfr[NJ];
#pragma unroll
      for (int i = 0; i < MI; ++i) {
        const int row = wm + i * 16 + (lane & 15);
        af[i] = *reinterpret_cast<const bf16x8*>(&A[row * 64 + ((kb ^ (row & 7)) << 3)]);
      }
#pragma unroll
      for (int j = 0; j < NJ; ++j) {
        const int row = wn + j * 16 + (lane & 15);
        bfr[j] = *reinterpret_cast<const bf16x8*>(&B[row * 64 + ((kb ^ (row & 7)) << 3)]);
      }
#pragma unroll
      for (int i = 0; i < MI; ++i)
#pragma unroll
        for (int j = 0; j < NJ; ++j)
          acc[i][j] = __builtin_amdgcn_mfma_f32_16x16x32_bf16(af[i], bfr[j], acc[i][j], 0, 0, 0);
    }
  };

  stage(0, 0);
  __syncthreads();
  int cur = 0;
  for (int k0 = 64; k0 < 512; k0 += 64) {
    stage(cur ^ 1, k0);
    compute(cur);
    __syncthreads();
    cur ^= 1;
  }
  compute(cur);

  if (OUT_BF16) {
    __syncthreads();
#pragma unroll
    for (int i = 0; i < MI; ++i)
#pragma unroll
      for (int j = 0; j < NJ; ++j)
#pragma unroll
        for (int r = 0; r < 4; ++r) {
          const int row = wm + i * 16 + (lane >> 4) * 4 + r;
          const int col = wn + j * 16 + (lane & 15);
          smem[row * BNv + col] = f2b(acc[i][j][r]);
        }
    __syncthreads();
    ushort* Y = reinterpret_cast<ushort*>(Yv);
    constexpr int CPT = BMv * BNv / 8 / 256;   // uint4 chunks per thread
#pragma unroll
    for (int p = 0; p < CPT; ++p) {
      const int c = p * 256 + t;
      const int row = c / (BNv / 8);
      const int cb  = c % (BNv / 8);
      *reinterpret_cast<uint4*>(&Y[(size_t)(bm + row) * ldY + bn + cb * 8]) =
          *reinterpret_cast<uint4*>(&smem[row * BNv + cb * 8]);
    }
  } else {
    float* Y = reinterpret_cast<float*>(Yv);
#pragma unroll
    for (int i = 0; i < MI; ++i) {
#pragma unroll
      for (int j = 0; j < NJ; ++j) {
        const int m = bm + wm + i * 16 + (lane >> 4) * 4;
        const int n = bn + wn + j * 16 + (lane & 15);
        const float bb = bias[n];
#pragma unroll
        for (int r = 0; r < 4; ++r)
          Y[(size_t)(m + r) * ldY + n] = acc[i][j][r] + bb + resid[(size_t)(m + r) * 512 + n];
      }
    }
  }
}

// ---------------------------------------------------------------------------
// Sparse gather attention, K AND V staged in LDS. One block per (b,s),
// 256 threads (4 waves). LDS 66.5 KB -> 2 blocks/CU.
// All 64 gathered-row loads (32 K + 32 V) issued async before ONE barrier.
// Phase 2: thread (h=t>>5, n=t&31): score from Ks (XOR-swizzled) + rpe
//          (hoisted pre-barrier), 32-lane shfl softmax -> pn in register.
// Phase 3: thread t -> ctx elems 2t,2t+1; V read from LDS (linear rows,
//          2-way bank aliasing = free); weight via __shfl within wave.
// ---------------------------------------------------------------------------
__global__ __launch_bounds__(256) void attn_k4(
    const ushort* __restrict__ qkv, const float* __restrict__ rpe,
    const int* __restrict__ qkm, ushort* __restrict__ ctx)
{
  __shared__ ushort Ks[32 * 512];   // K row n at n*512, 16B-block-swizzled
  __shared__ ushort Vs[32 * 512];   // V row n at n*512, linear
  __shared__ float  qs[512];

  const int bs = blockIdx.x;
  const int b  = bs >> 11;
  const int s  = bs & 2047;
  const int t  = threadIdx.x;
  const int wv = t >> 6, lane = t & 63;

  // q: one packed uint (2 bf16) per thread
  const uint qu = *reinterpret_cast<const uint*>(qkv + (size_t)bs * QKV + 2 * t);
  qs[2 * t]     = __uint_as_float(qu << 16);
  qs[2 * t + 1] = __uint_as_float(qu & 0xffff0000u);

  // per-thread gather index + rpe (hoisted before barrier)
  const int iv = qkm[s * NKk + (lane & 31)];
  const float rv = rpe[((size_t)bs * NKk + (t & 31)) * Hh + (t >> 5)];

  // stage 32 K rows + 32 V rows, all async before one barrier
#pragma unroll
  for (int r = 0; r < 8; ++r) {
    const int n = r * 4 + wv;                 // wave-uniform row
    int im = qkm[s * NKk + n];
    im = im < 0 ? 0 : im;
    const ushort* base = qkv + (size_t)(b * Ss + im) * QKV;
    gload_lds16(base + 512  + ((lane ^ (n & 7)) * 8), &Ks[n * 512]);
    gload_lds16(base + 1024 + lane * 8,               &Vs[n * 512]);
  }

  __syncthreads();   // drains vmcnt (all 64 row-loads) + lgkmcnt

  // ---- phase 2: scores + softmax ----
  const int h = t >> 5;
  const int n = t & 31;
  const bool valid = (iv >= 0);

  float2 a2 = make_float2(0.f, 0.f);
#pragma unroll
  for (int j = 0; j < 8; ++j) {
    const int blk = (h * 8 + j) ^ (n & 7);
    const uint4 kk = *reinterpret_cast<const uint4*>(&Ks[n * 512 + blk * 8]);
    const float4 qa = *reinterpret_cast<const float4*>(&qs[h * 64 + j * 8]);
    const float4 qb = *reinterpret_cast<const float4*>(&qs[h * 64 + j * 8 + 4]);
    a2.x += qa.x * __uint_as_float(kk.x << 16);
    a2.y += qa.y * __uint_as_float(kk.x & 0xffff0000u);
    a2.x += qa.z * __uint_as_float(kk.y << 16);
    a2.y += qa.w * __uint_as_float(kk.y & 0xffff0000u);
    a2.x += qb.x * __uint_as_float(kk.z << 16);
    a2.y += qb.y * __uint_as_float(kk.z & 0xffff0000u);
    a2.x += qb.z * __uint_as_float(kk.w << 16);
    a2.y += qb.w * __uint_as_float(kk.w & 0xffff0000u);
  }
  float sc = a2.x + a2.y + rv;
  sc = valid ? sc * 0.125f : -1e30f;

  float mx = sc;
#pragma unroll
  for (int m = 16; m >= 1; m >>= 1) mx = fmaxf(mx, __shfl_xor(mx, m, 32));
  const float p = valid ? __expf(sc - mx) : 0.f;
  float sum = p;
#pragma unroll
  for (int m = 16; m >= 1; m >>= 1) sum += __shfl_xor(sum, m, 32);
  const float pn = (sum > 0.f) ? (p / sum) : 0.f;

  // ---- phase 3: ctx elems 2t, 2t+1 from LDS V ----
  const int e = 2 * t;   // elem in [0,512); head h = e>>6 == t>>5 (matches)
  float c0 = 0.f, c1 = 0.f;
#pragma unroll
  for (int n2 = 0; n2 < 32; ++n2) {
    const float a = __shfl(pn, (lane & 32) + n2, 64);
    const uint vvu = *reinterpret_cast<const uint*>(&Vs[n2 * 512 + e]);
    c0 += a * __uint_as_float(vvu << 16);
    c1 += a * __uint_as_float(vvu & 0xffff0000u);
  }
  const uint packed = (uint)f2b(c0) | ((uint)f2b(c1) << 16);
  *reinterpret_cast<uint*>(&ctx[(size_t)bs * 512 + e]) = packed;
}

// ---------------------------------------------------------------------------
// In-place row LayerNorm over DM=512. One wave per row, 4 rows per block.
// ---------------------------------------------------------------------------
__global__ __launch_bounds__(256) void ln_k(
    float* __restrict__ x, const float* __restrict__ g,
    const float* __restrict__ bta)
{
  const int w    = threadIdx.x >> 6;
  const int lane = threadIdx.x & 63;
  const int row  = blockIdx.x * 4 + w;

  float4* xr = reinterpret_cast<float4*>(x + (size_t)row * 512);
  const float4 v0 = xr[lane];
  const float4 v1 = xr[lane + 64];

  float sum = v0.x + v0.y + v0.z + v0.w + v1.x + v1.y + v1.z + v1.w;
  float sq  = v0.x * v0.x + v0.y * v0.y + v0.z * v0.z + v0.w * v0.w
            + v1.x * v1.x + v1.y * v1.y + v1.z * v1.z + v1.w * v1.w;
#pragma unroll
  for (int m = 32; m >= 1; m >>= 1) {
    sum += __shfl_xor(sum, m, 64);
    sq  += __shfl_xor(sq,  m, 64);
  }
  const float mu  = sum * (1.f / 512.f);
  const float var = sq * (1.f / 512.f) - mu * mu;
  const float rs  = rsqrtf(var + 1e-6f);

  const float4 g0 = reinterpret_cast<const float4*>(g)[lane];
  const float4 g1 = reinterpret_cast<const float4*>(g)[lane + 64];
  const float4 b0 = reinterpret_cast<const float4*>(bta)[lane];
  const float4 b1 = reinterpret_cast<const float4*>(bta)[lane + 64];

  float4 o0, o1;
  o0.x = (v0.x - mu) * rs * g0.x + b0.x;
  o0.y = (v0.y - mu) * rs * g0.y + b0.y;
  o0.z = (v0.z - mu) * rs * g0.z + b0.z;
  o0.w = (v0.w - mu) * rs * g0.w + b0.w;
  o1.x = (v1.x - mu) * rs * g1.x + b1.x;
  o1.y = (v1.y - mu) * rs * g1.y + b1.y;
  o1.z = (v1.z - mu) * rs * g1.z + b1.z;
  o1.w = (v1.w - mu) * rs * g1.w + b1.w;
  xr[lane]      = o0;
  xr[lane + 64] = o1;
}

extern "C" void kernel_launch(void* const* d_in, const int* in_sizes, int n_in,
                              void* d_out, int out_size, void* d_ws, size_t ws_size,
                              hipStream_t stream) {
  const float* hs  = (const float*)d_in[0];
  const float* rpe = (const float*)d_in[1];
  const int*   qkm = (const int*)d_in[2];
  const float* wq  = (const float*)d_in[4];
  const float* wk  = (const float*)d_in[5];
  const float* wv  = (const float*)d_in[6];
  const float* fcw = (const float*)d_in[7];
  const float* fcb = (const float*)d_in[8];
  const float* lng = (const float*)d_in[9];
  const float* lnb = (const float*)d_in[10];
  float* out = (float*)d_out;

  // workspace (ushort elems): Xb 2M | Wt3 0.75M | Wtf 0.25M | qkv 6M | cxb 2M
  ushort* Xb  = (ushort*)d_ws;
  ushort* Wt3 = Xb  + (size_t)Mm * DMm;
  ushort* Wtf = Wt3 + (size_t)3 * DMm * DMm;
  ushort* qkv = Wtf + (size_t)DMm * DMm;
  ushort* cxb = qkv + (size_t)Mm * QKV;

  cvt_all_k<<<dim3(8, 8, 8), 256, 0, stream>>>(hs, wq, wk, wv, fcw, Xb, Wt3, Wtf);

  // fused QKV GEMM: 128x96 tiles -> 32x16 = 512 blocks = 2.00/CU
  gemm_dbuf<1, 128, 96><<<dim3(Mm / 128, QKV / 96), 256, 0, stream>>>(
      Xb, Wt3, qkv, nullptr, nullptr, QKV);

  attn_k4<<<Mm, 256, 0, stream>>>(qkv, rpe, qkm, cxb);

  // fc GEMM: 64x64 tiles -> 64x8 = 512 blocks = 2.00/CU
  gemm_dbuf<0, 64, 64><<<dim3(Mm / 64, DMm / 64), 256, 0, stream>>>(
      cxb, Wtf, out, fcb, hs, DMm);
  ln_k<<<Mm / 4, 256, 0, stream>>>(out, lng, lnb);
}

// Round 7
// 57.152 us; speedup vs baseline: 1.1049x; 1.1049x over previous
//
#include <hip/hip_runtime.h>
#include <hip/hip_bf16.h>

// (B, S, NK, H, D, DM) = (2, 2048, 32, 8, 64, 512)
constexpr int Bb  = 2;
constexpr int Ss  = 2048;
constexpr int NKk = 32;
constexpr int Hh  = 8;
constexpr int DMm = 512;
constexpr int Mm  = Bb * Ss;   // 4096 rows
constexpr int QKV = 1536;      // concat row stride

typedef __attribute__((ext_vector_type(8))) short bf16x8;
typedef __attribute__((ext_vector_type(4))) float f32x4;

__device__ __forceinline__ float b2f(unsigned short u) {
  return __uint_as_float((unsigned)u << 16);
}
__device__ __forceinline__ unsigned short f2b(float f) {
  unsigned u = __float_as_uint(f);
  unsigned r = (u + 0x7fffu + ((u >> 16) & 1u)) >> 16;   // RNE
  return (unsigned short)r;
}
__device__ __forceinline__ void gload_lds16(const ushort* g, ushort* l) {
  __builtin_amdgcn_global_load_lds(
      (const __attribute__((address_space(1))) void*)g,
      (__attribute__((address_space(3))) void*)l, 16, 0, 0);
}

// ---------------------------------------------------------------------------
// Merged conversion kernel. grid (8,8,8), 256 threads.
//  z<4 : weight transpose+convert, W fp32 [k][n] (512x512) -> Wt bf16 [n][k]
//  z>=4: hs fp32 -> Xb bf16 flat
// ---------------------------------------------------------------------------
__global__ __launch_bounds__(256) void cvt_all_k(
    const float* __restrict__ hs,
    const float* __restrict__ Wq, const float* __restrict__ Wk,
    const float* __restrict__ Wv, const float* __restrict__ Wf,
    ushort* __restrict__ Xb, ushort* __restrict__ Wt3, ushort* __restrict__ Wtf)
{
  __shared__ float tile[64][65];
  const int z = blockIdx.z;
  const int t = threadIdx.x;

  if (z >= 4) {
    const int cid = (z - 4) * 64 + blockIdx.x * 8 + blockIdx.y;   // 0..255
    const size_t base8 = (size_t)cid * 1024;                      // uint4 units
#pragma unroll
    for (int it = 0; it < 4; ++it) {
      const size_t i = base8 + it * 256 + t;
      const float4 a = reinterpret_cast<const float4*>(hs)[2 * i];
      const float4 b = reinterpret_cast<const float4*>(hs)[2 * i + 1];
      ushort o[8] = {f2b(a.x), f2b(a.y), f2b(a.z), f2b(a.w),
                     f2b(b.x), f2b(b.y), f2b(b.z), f2b(b.w)};
      reinterpret_cast<uint4*>(Xb)[i] = *reinterpret_cast<uint4*>(o);
    }
    return;
  }

  const float* W = (z == 0) ? Wq : (z == 1) ? Wk : (z == 2) ? Wv : Wf;
  ushort* Wt = (z < 3) ? (Wt3 + (size_t)z * 512 * 512) : Wtf;

  const int k0 = blockIdx.x * 64, n0 = blockIdx.y * 64;
#pragma unroll
  for (int p = 0; p < 4; ++p) {
    const int r = (t >> 4) + p * 16, c = (t & 15) * 4;
    const float4 v = *reinterpret_cast<const float4*>(&W[(size_t)(k0 + r) * 512 + n0 + c]);
    tile[r][c] = v.x; tile[r][c + 1] = v.y; tile[r][c + 2] = v.z; tile[r][c + 3] = v.w;
  }
  __syncthreads();
  const int n = t >> 2, ks = (t & 3) * 16;
  ushort o[16];
#pragma unroll
  for (int i = 0; i < 16; ++i) o[i] = f2b(tile[ks + i][n]);
  *reinterpret_cast<uint4*>(&Wt[(size_t)(n0 + n) * 512 + k0 + ks])     = *reinterpret_cast<uint4*>(&o[0]);
  *reinterpret_cast<uint4*>(&Wt[(size_t)(n0 + n) * 512 + k0 + ks + 8]) = *reinterpret_cast<uint4*>(&o[8]);
}

// ---------------------------------------------------------------------------
// 2-phase double-buffered bf16 MFMA GEMM. Y = Xb @ Wt^T.
// BM=BMv, BN=BNv, BK=64. 4 waves (2x2); wave tile (BMv/2) x (BNv/2).
// Staging: global_load_lds w=16, SOURCE-swizzled 16B blocks; reads same XOR.
// ---------------------------------------------------------------------------
template <int OUT_BF16, int BMv, int BNv>
__global__ __launch_bounds__(256) void gemm_dbuf(
    const ushort* __restrict__ Xb, const ushort* __restrict__ Wt,
    void* __restrict__ Yv, const float* __restrict__ bias,
    const float* __restrict__ resid, int ldY)
{
  constexpr int MI = BMv / 32;                    // A-frags per wave
  constexpr int NJ = BNv / 32;                    // B-frags per wave
  constexpr int ASZ = BMv * 64;                   // ushorts per A buffer
  __shared__ ushort smem[2 * ASZ + 2 * BNv * 64];

  const int bm = blockIdx.x * BMv;
  const int bn = blockIdx.y * BNv;
  const int t  = threadIdx.x;
  const int wave = t >> 6, lane = t & 63;
  const int wm = (wave >> 1) * (BMv / 2);
  const int wn = (wave & 1) * (BNv / 2);

  f32x4 acc[MI][NJ] = {};

  auto stage = [&](int buf, int k0) {
    ushort* A = smem + buf * ASZ;
    ushort* B = smem + 2 * ASZ + buf * (BNv * 64);
#pragma unroll
    for (int p = 0; p < MI; ++p) {                // A: BMv x 64 bf16
      const int i = p * 256 + t;
      const int row = i >> 3, sb = i & 7;
      gload_lds16(Xb + (size_t)(bm + row) * 512 + k0 + ((sb ^ (row & 7)) << 3),
                  &A[(size_t)(p * 256 + wave * 64) * 8]);
    }
#pragma unroll
    for (int p = 0; p < NJ; ++p) {                // B: BNv x 64 bf16
      const int i = p * 256 + t;
      const int row = i >> 3, sb = i & 7;
      gload_lds16(Wt + (size_t)(bn + row) * 512 + k0 + ((sb ^ (row & 7)) << 3),
                  &B[(size_t)(p * 256 + wave * 64) * 8]);
    }
  };

  auto compute = [&](int buf) {
    const ushort* A = smem + buf * ASZ;
    const ushort* B = smem + 2 * ASZ + buf * (BNv * 64);
#pragma unroll
    for (int ks = 0; ks < 2; ++ks) {
      const int kb = ks * 4 + (lane >> 4);
      bf16x8 af[MI], bfr[NJ];
#pragma unroll
      for (int i = 0; i < MI; ++i) {
        const int row = wm + i * 16 + (lane & 15);
        af[i] = *reinterpret_cast<const bf16x8*>(&A[row * 64 + ((kb ^ (row & 7)) << 3)]);
      }
#pragma unroll
      for (int j = 0; j < NJ; ++j) {
        const int row = wn + j * 16 + (lane & 15);
        bfr[j] = *reinterpret_cast<const bf16x8*>(&B[row * 64 + ((kb ^ (row & 7)) << 3)]);
      }
#pragma unroll
      for (int i = 0; i < MI; ++i)
#pragma unroll
        for (int j = 0; j < NJ; ++j)
          acc[i][j] = __builtin_amdgcn_mfma_f32_16x16x32_bf16(af[i], bfr[j], acc[i][j], 0, 0, 0);
    }
  };

  stage(0, 0);
  __syncthreads();
  int cur = 0;
  for (int k0 = 64; k0 < 512; k0 += 64) {
    stage(cur ^ 1, k0);
    compute(cur);
    __syncthreads();
    cur ^= 1;
  }
  compute(cur);

  if (OUT_BF16) {
    __syncthreads();
#pragma unroll
    for (int i = 0; i < MI; ++i)
#pragma unroll
      for (int j = 0; j < NJ; ++j)
#pragma unroll
        for (int r = 0; r < 4; ++r) {
          const int row = wm + i * 16 + (lane >> 4) * 4 + r;
          const int col = wn + j * 16 + (lane & 15);
          smem[row * BNv + col] = f2b(acc[i][j][r]);
        }
    __syncthreads();
    ushort* Y = reinterpret_cast<ushort*>(Yv);
    constexpr int CPT = BMv * BNv / 8 / 256;   // uint4 chunks per thread
#pragma unroll
    for (int p = 0; p < CPT; ++p) {
      const int c = p * 256 + t;
      const int row = c / (BNv / 8);
      const int cb  = c % (BNv / 8);
      *reinterpret_cast<uint4*>(&Y[(size_t)(bm + row) * ldY + bn + cb * 8]) =
          *reinterpret_cast<uint4*>(&smem[row * BNv + cb * 8]);
    }
  } else {
    float* Y = reinterpret_cast<float*>(Yv);
#pragma unroll
    for (int i = 0; i < MI; ++i) {
#pragma unroll
      for (int j = 0; j < NJ; ++j) {
        const int m = bm + wm + i * 16 + (lane >> 4) * 4;
        const int n = bn + wn + j * 16 + (lane & 15);
        const float bb = bias[n];
#pragma unroll
        for (int r = 0; r < 4; ++r)
          Y[(size_t)(m + r) * ldY + n] = acc[i][j][r] + bb + resid[(size_t)(m + r) * 512 + n];
      }
    }
  }
}

// ---------------------------------------------------------------------------
// Sparse gather attention. One block per (b,s), 256 threads (4 waves).
// LDS: K rows only (34.8 KB -> 4 blocks/CU, as round-5).
// NEW vs round-5: all 32 V values per thread prefetched into REGISTERS
// before the barrier (addresses depend only on iv) — they fly concurrently
// with the K global_load_lds batch; phase 3 is pure register FMA.
// ---------------------------------------------------------------------------
__global__ __launch_bounds__(256) void attn_k5(
    const ushort* __restrict__ qkv, const float* __restrict__ rpe,
    const int* __restrict__ qkm, ushort* __restrict__ ctx)
{
  __shared__ ushort Ks[32 * 512];   // K row n at n*512, 16B-block-swizzled
  __shared__ float  qs[512];

  const int bs = blockIdx.x;
  const int b  = bs >> 11;
  const int s  = bs & 2047;
  const int t  = threadIdx.x;
  const int wv = t >> 6, lane = t & 63;

  // q: one packed uint (2 bf16) per thread -> LDS fp32
  const uint qu = *reinterpret_cast<const uint*>(qkv + (size_t)bs * QKV + 2 * t);
  qs[2 * t]     = __uint_as_float(qu << 16);
  qs[2 * t + 1] = __uint_as_float(qu & 0xffff0000u);

  // per-thread gather index + rpe, hoisted pre-barrier
  const int iv = qkm[s * NKk + (lane & 31)];
  const float rv = rpe[((size_t)bs * NKk + (t & 31)) * Hh + (t >> 5)];

  // stage 32 K rows async into LDS (SOURCE-swizzled 16B blocks)
#pragma unroll
  for (int r = 0; r < 8; ++r) {
    const int n = r * 4 + wv;                 // wave-uniform row
    int im = qkm[s * NKk + n];
    im = im < 0 ? 0 : im;
    const ushort* gsrc = qkv + (size_t)(b * Ss + im) * QKV + 512
                       + ((lane ^ (n & 7)) * 8);
    gload_lds16(gsrc, &Ks[n * 512]);
  }

  // V prefetch to registers (independent of LDS; concurrent with K stage)
  const ushort* vbase = qkv + (size_t)b * Ss * QKV + 1024;
  const int e = 2 * t;   // ctx elems 2t, 2t+1; head h = t>>5 matches phase 2
  uint vvu[32];
#pragma unroll
  for (int n2 = 0; n2 < 32; ++n2) {
    int row = __shfl(iv, (lane & 32) + n2, 64);
    row = row < 0 ? 0 : row;
    vvu[n2] = *reinterpret_cast<const uint*>(&vbase[(size_t)row * QKV + (e & 511)]);
  }

  __syncthreads();   // drains vmcnt (K stage + V prefetch) + lgkmcnt

  // ---- phase 2: scores + softmax (thread = (h = t>>5, n = t&31)) ----
  const int h = t >> 5;
  const int n = t & 31;
  const bool valid = (iv >= 0);

  float2 a2 = make_float2(0.f, 0.f);
#pragma unroll
  for (int j = 0; j < 8; ++j) {
    const int blk = (h * 8 + j) ^ (n & 7);
    const uint4 kk = *reinterpret_cast<const uint4*>(&Ks[n * 512 + blk * 8]);
    const float4 qa = *reinterpret_cast<const float4*>(&qs[h * 64 + j * 8]);
    const float4 qb = *reinterpret_cast<const float4*>(&qs[h * 64 + j * 8 + 4]);
    a2.x += qa.x * __uint_as_float(kk.x << 16);
    a2.y += qa.y * __uint_as_float(kk.x & 0xffff0000u);
    a2.x += qa.z * __uint_as_float(kk.y << 16);
    a2.y += qa.w * __uint_as_float(kk.y & 0xffff0000u);
    a2.x += qb.x * __uint_as_float(kk.z << 16);
    a2.y += qb.y * __uint_as_float(kk.z & 0xffff0000u);
    a2.x += qb.z * __uint_as_float(kk.w << 16);
    a2.y += qb.w * __uint_as_float(kk.w & 0xffff0000u);
  }
  float sc = a2.x + a2.y + rv;
  sc = valid ? sc * 0.125f : -1e30f;

  float mx = sc;
#pragma unroll
  for (int m = 16; m >= 1; m >>= 1) mx = fmaxf(mx, __shfl_xor(mx, m, 32));
  const float p = valid ? __expf(sc - mx) : 0.f;
  float sum = p;
#pragma unroll
  for (int m = 16; m >= 1; m >>= 1) sum += __shfl_xor(sum, m, 32);
  const float pn = (sum > 0.f) ? (p / sum) : 0.f;

  // ---- phase 3: ctx elems 2t, 2t+1 — pure register FMA ----
  float c0 = 0.f, c1 = 0.f;
#pragma unroll
  for (int n2 = 0; n2 < 32; ++n2) {
    const float a = __shfl(pn, (lane & 32) + n2, 64);
    c0 += a * __uint_as_float(vvu[n2] << 16);
    c1 += a * __uint_as_float(vvu[n2] & 0xffff0000u);
  }
  const uint packed = (uint)f2b(c0) | ((uint)f2b(c1) << 16);
  *reinterpret_cast<uint*>(&ctx[(size_t)bs * 512 + e]) = packed;
}

// ---------------------------------------------------------------------------
// In-place row LayerNorm over DM=512. One wave per row, 4 rows per block.
// ---------------------------------------------------------------------------
__global__ __launch_bounds__(256) void ln_k(
    float* __restrict__ x, const float* __restrict__ g,
    const float* __restrict__ bta)
{
  const int w    = threadIdx.x >> 6;
  const int lane = threadIdx.x & 63;
  const int row  = blockIdx.x * 4 + w;

  float4* xr = reinterpret_cast<float4*>(x + (size_t)row * 512);
  const float4 v0 = xr[lane];
  const float4 v1 = xr[lane + 64];

  float sum = v0.x + v0.y + v0.z + v0.w + v1.x + v1.y + v1.z + v1.w;
  float sq  = v0.x * v0.x + v0.y * v0.y + v0.z * v0.z + v0.w * v0.w
            + v1.x * v1.x + v1.y * v1.y + v1.z * v1.z + v1.w * v1.w;
#pragma unroll
  for (int m = 32; m >= 1; m >>= 1) {
    sum += __shfl_xor(sum, m, 64);
    sq  += __shfl_xor(sq,  m, 64);
  }
  const float mu  = sum * (1.f / 512.f);
  const float var = sq * (1.f / 512.f) - mu * mu;
  const float rs  = rsqrtf(var + 1e-6f);

  const float4 g0 = reinterpret_cast<const float4*>(g)[lane];
  const float4 g1 = reinterpret_cast<const float4*>(g)[lane + 64];
  const float4 b0 = reinterpret_cast<const float4*>(bta)[lane];
  const float4 b1 = reinterpret_cast<const float4*>(bta)[lane + 64];

  float4 o0, o1;
  o0.x = (v0.x - mu) * rs * g0.x + b0.x;
  o0.y = (v0.y - mu) * rs * g0.y + b0.y;
  o0.z = (v0.z - mu) * rs * g0.z + b0.z;
  o0.w = (v0.w - mu) * rs * g0.w + b0.w;
  o1.x = (v1.x - mu) * rs * g1.x + b1.x;
  o1.y = (v1.y - mu) * rs * g1.y + b1.y;
  o1.z = (v1.z - mu) * rs * g1.z + b1.z;
  o1.w = (v1.w - mu) * rs * g1.w + b1.w;
  xr[lane]      = o0;
  xr[lane + 64] = o1;
}

extern "C" void kernel_launch(void* const* d_in, const int* in_sizes, int n_in,
                              void* d_out, int out_size, void* d_ws, size_t ws_size,
                              hipStream_t stream) {
  const float* hs  = (const float*)d_in[0];
  const float* rpe = (const float*)d_in[1];
  const int*   qkm = (const int*)d_in[2];
  const float* wq  = (const float*)d_in[4];
  const float* wk  = (const float*)d_in[5];
  const float* wv  = (const float*)d_in[6];
  const float* fcw = (const float*)d_in[7];
  const float* fcb = (const float*)d_in[8];
  const float* lng = (const float*)d_in[9];
  const float* lnb = (const float*)d_in[10];
  float* out = (float*)d_out;

  // workspace (ushort elems): Xb 2M | Wt3 0.75M | Wtf 0.25M | qkv 6M | cxb 2M
  ushort* Xb  = (ushort*)d_ws;
  ushort* Wt3 = Xb  + (size_t)Mm * DMm;
  ushort* Wtf = Wt3 + (size_t)3 * DMm * DMm;
  ushort* qkv = Wtf + (size_t)DMm * DMm;
  ushort* cxb = qkv + (size_t)Mm * QKV;

  cvt_all_k<<<dim3(8, 8, 8), 256, 0, stream>>>(hs, wq, wk, wv, fcw, Xb, Wt3, Wtf);

  // fused QKV GEMM: 128x96 tiles -> 32x16 = 512 blocks = 2.00/CU (round-5)
  gemm_dbuf<1, 128, 96><<<dim3(Mm / 128, QKV / 96), 256, 0, stream>>>(
      Xb, Wt3, qkv, nullptr, nullptr, QKV);

  attn_k5<<<Mm, 256, 0, stream>>>(qkv, rpe, qkm, cxb);

  // fc GEMM: 128x64 tiles -> 32x8 = 256 blocks = 1.00/CU (round-5)
  gemm_dbuf<0, 128, 64><<<dim3(Mm / 128, DMm / 64), 256, 0, stream>>>(
      cxb, Wtf, out, fcb, hs, DMm);
  ln_k<<<Mm / 4, 256, 0, stream>>>(out, lng, lnb);
}

// Round 8
// 55.195 us; speedup vs baseline: 1.1440x; 1.0355x over previous
//
#include <hip/hip_runtime.h>
#include <hip/hip_bf16.h>

// (B, S, NK, H, D, DM) = (2, 2048, 32, 8, 64, 512)
constexpr int Bb  = 2;
constexpr int Ss  = 2048;
constexpr int NKk = 32;
constexpr int Hh  = 8;
constexpr int DMm = 512;
constexpr int Mm  = Bb * Ss;   // 4096 rows
constexpr int QKV = 1536;      // concat row stride

typedef __attribute__((ext_vector_type(8))) short bf16x8;
typedef __attribute__((ext_vector_type(4))) float f32x4;

__device__ __forceinline__ float b2f(unsigned short u) {
  return __uint_as_float((unsigned)u << 16);
}
__device__ __forceinline__ unsigned short f2b(float f) {
  unsigned u = __float_as_uint(f);
  unsigned r = (u + 0x7fffu + ((u >> 16) & 1u)) >> 16;   // RNE
  return (unsigned short)r;
}
__device__ __forceinline__ void gload_lds16(const ushort* g, ushort* l) {
  __builtin_amdgcn_global_load_lds(
      (const __attribute__((address_space(1))) void*)g,
      (__attribute__((address_space(3))) void*)l, 16, 0, 0);
}

// ---------------------------------------------------------------------------
// Merged conversion kernel. grid (8,8,8), 256 threads.
//  z<4 : weight transpose+convert, W fp32 [k][n] (512x512) -> Wt bf16 [n][k]
//  z>=4: hs fp32 -> Xb bf16 flat
// ---------------------------------------------------------------------------
__global__ __launch_bounds__(256) void cvt_all_k(
    const float* __restrict__ hs,
    const float* __restrict__ Wq, const float* __restrict__ Wk,
    const float* __restrict__ Wv, const float* __restrict__ Wf,
    ushort* __restrict__ Xb, ushort* __restrict__ Wt3, ushort* __restrict__ Wtf)
{
  __shared__ float tile[64][65];
  const int z = blockIdx.z;
  const int t = threadIdx.x;

  if (z >= 4) {
    const int cid = (z - 4) * 64 + blockIdx.x * 8 + blockIdx.y;   // 0..255
    const size_t base8 = (size_t)cid * 1024;                      // uint4 units
#pragma unroll
    for (int it = 0; it < 4; ++it) {
      const size_t i = base8 + it * 256 + t;
      const float4 a = reinterpret_cast<const float4*>(hs)[2 * i];
      const float4 b = reinterpret_cast<const float4*>(hs)[2 * i + 1];
      ushort o[8] = {f2b(a.x), f2b(a.y), f2b(a.z), f2b(a.w),
                     f2b(b.x), f2b(b.y), f2b(b.z), f2b(b.w)};
      reinterpret_cast<uint4*>(Xb)[i] = *reinterpret_cast<uint4*>(o);
    }
    return;
  }

  const float* W = (z == 0) ? Wq : (z == 1) ? Wk : (z == 2) ? Wv : Wf;
  ushort* Wt = (z < 3) ? (Wt3 + (size_t)z * 512 * 512) : Wtf;

  const int k0 = blockIdx.x * 64, n0 = blockIdx.y * 64;
#pragma unroll
  for (int p = 0; p < 4; ++p) {
    const int r = (t >> 4) + p * 16, c = (t & 15) * 4;
    const float4 v = *reinterpret_cast<const float4*>(&W[(size_t)(k0 + r) * 512 + n0 + c]);
    tile[r][c] = v.x; tile[r][c + 1] = v.y; tile[r][c + 2] = v.z; tile[r][c + 3] = v.w;
  }
  __syncthreads();
  const int n = t >> 2, ks = (t & 3) * 16;
  ushort o[16];
#pragma unroll
  for (int i = 0; i < 16; ++i) o[i] = f2b(tile[ks + i][n]);
  *reinterpret_cast<uint4*>(&Wt[(size_t)(n0 + n) * 512 + k0 + ks])     = *reinterpret_cast<uint4*>(&o[0]);
  *reinterpret_cast<uint4*>(&Wt[(size_t)(n0 + n) * 512 + k0 + ks + 8]) = *reinterpret_cast<uint4*>(&o[8]);
}

// ---------------------------------------------------------------------------
// Counted-vmcnt pipelined bf16 MFMA GEMM (T4). Y = Xb @ Wt^T.
// BM=BMv, BN=BNv, BK=64, K=512 (8 steps). 4 waves (2x2).
// Per step i: issue stage(i+1) -> s_waitcnt vmcnt(STG) [waits ONLY tile i;
// tile i+1's STG loads stay in flight] -> s_barrier -> compute(i) ->
// s_barrier (no vmcnt drain!). Staging: global_load_lds w=16, SOURCE-
// swizzled 16B blocks; ds_reads apply the same XOR.
// ---------------------------------------------------------------------------
template <int OUT_BF16, int BMv, int BNv>
__global__ __launch_bounds__(256) void gemm_pipe(
    const ushort* __restrict__ Xb, const ushort* __restrict__ Wt,
    void* __restrict__ Yv, const float* __restrict__ bias,
    const float* __restrict__ resid, int ldY)
{
  constexpr int MI  = BMv / 32;                   // A-frags per wave
  constexpr int NJ  = BNv / 32;                   // B-frags per wave
  constexpr int STG = MI + NJ;                    // gload_lds per wave/stage
  constexpr int ASZ = BMv * 64;                   // ushorts per A buffer
  __shared__ ushort smem[2 * ASZ + 2 * BNv * 64];

  const int bm = blockIdx.x * BMv;
  const int bn = blockIdx.y * BNv;
  const int t  = threadIdx.x;
  const int wave = t >> 6, lane = t & 63;
  const int wm = (wave >> 1) * (BMv / 2);
  const int wn = (wave & 1) * (BNv / 2);

  f32x4 acc[MI][NJ] = {};

  auto stage = [&](int buf, int k0) {
    ushort* A = smem + buf * ASZ;
    ushort* B = smem + 2 * ASZ + buf * (BNv * 64);
#pragma unroll
    for (int p = 0; p < MI; ++p) {                // A: BMv x 64 bf16
      const int i = p * 256 + t;
      const int row = i >> 3, sb = i & 7;
      gload_lds16(Xb + (size_t)(bm + row) * 512 + k0 + ((sb ^ (row & 7)) << 3),
                  &A[(size_t)(p * 256 + wave * 64) * 8]);
    }
#pragma unroll
    for (int p = 0; p < NJ; ++p) {                // B: BNv x 64 bf16
      const int i = p * 256 + t;
      const int row = i >> 3, sb = i & 7;
      gload_lds16(Wt + (size_t)(bn + row) * 512 + k0 + ((sb ^ (row & 7)) << 3),
                  &B[(size_t)(p * 256 + wave * 64) * 8]);
    }
  };

  auto compute = [&](int buf) {
    const ushort* A = smem + buf * ASZ;
    const ushort* B = smem + 2 * ASZ + buf * (BNv * 64);
#pragma unroll
    for (int ks = 0; ks < 2; ++ks) {
      const int kb = ks * 4 + (lane >> 4);
      bf16x8 af[MI], bfr[NJ];
#pragma unroll
      for (int i = 0; i < MI; ++i) {
        const int row = wm + i * 16 + (lane & 15);
        af[i] = *reinterpret_cast<const bf16x8*>(&A[row * 64 + ((kb ^ (row & 7)) << 3)]);
      }
#pragma unroll
      for (int j = 0; j < NJ; ++j) {
        const int row = wn + j * 16 + (lane & 15);
        bfr[j] = *reinterpret_cast<const bf16x8*>(&B[row * 64 + ((kb ^ (row & 7)) << 3)]);
      }
#pragma unroll
      for (int i = 0; i < MI; ++i)
#pragma unroll
        for (int j = 0; j < NJ; ++j)
          acc[i][j] = __builtin_amdgcn_mfma_f32_16x16x32_bf16(af[i], bfr[j], acc[i][j], 0, 0, 0);
    }
  };

  stage(0, 0);
  int cur = 0;
#pragma unroll
  for (int i = 0; i < 8; ++i) {
    if (i < 7) {
      stage(cur ^ 1, (i + 1) * 64);   // next tile's loads fly across barriers
      asm volatile("s_waitcnt vmcnt(%0)" :: "n"(STG) : "memory");
    } else {
      asm volatile("s_waitcnt vmcnt(0)" ::: "memory");
    }
    __builtin_amdgcn_sched_barrier(0);
    __builtin_amdgcn_s_barrier();     // tile i ready in LDS for all waves
    compute(cur);
    __builtin_amdgcn_sched_barrier(0);
    __builtin_amdgcn_s_barrier();     // all waves done reading tile i
    cur ^= 1;
  }

  if (OUT_BF16) {
#pragma unroll
    for (int i = 0; i < MI; ++i)
#pragma unroll
      for (int j = 0; j < NJ; ++j)
#pragma unroll
        for (int r = 0; r < 4; ++r) {
          const int row = wm + i * 16 + (lane >> 4) * 4 + r;
          const int col = wn + j * 16 + (lane & 15);
          smem[row * BNv + col] = f2b(acc[i][j][r]);
        }
    __syncthreads();
    ushort* Y = reinterpret_cast<ushort*>(Yv);
    constexpr int CPT = BMv * BNv / 8 / 256;   // uint4 chunks per thread
#pragma unroll
    for (int p = 0; p < CPT; ++p) {
      const int c = p * 256 + t;
      const int row = c / (BNv / 8);
      const int cb  = c % (BNv / 8);
      *reinterpret_cast<uint4*>(&Y[(size_t)(bm + row) * ldY + bn + cb * 8]) =
          *reinterpret_cast<uint4*>(&smem[row * BNv + cb * 8]);
    }
  } else {
    float* Y = reinterpret_cast<float*>(Yv);
#pragma unroll
    for (int i = 0; i < MI; ++i) {
#pragma unroll
      for (int j = 0; j < NJ; ++j) {
        const int m = bm + wm + i * 16 + (lane >> 4) * 4;
        const int n = bn + wn + j * 16 + (lane & 15);
        const float bb = bias[n];
#pragma unroll
        for (int r = 0; r < 4; ++r)
          Y[(size_t)(m + r) * ldY + n] = acc[i][j][r] + bb + resid[(size_t)(m + r) * 512 + n];
      }
    }
  }
}

// ---------------------------------------------------------------------------
// Sparse gather attention (round-5 proven version). One block per (b,s),
// 256 threads (4 waves). K rows staged in LDS (34.8 KB -> 4 blocks/CU);
// V read from L2 in phase 3 (covered by TLP).
// ---------------------------------------------------------------------------
__global__ __launch_bounds__(256) void attn_k3(
    const ushort* __restrict__ qkv, const float* __restrict__ rpe,
    const int* __restrict__ qkm, ushort* __restrict__ ctx)
{
  __shared__ ushort Ks[32 * 512];   // row n at n*512, 16B-block-swizzled
  __shared__ float  qs[512];

  const int bs = blockIdx.x;
  const int b  = bs >> 11;
  const int s  = bs & 2047;
  const int t  = threadIdx.x;
  const int wv = t >> 6, lane = t & 63;

  const ushort* qrow = qkv + (size_t)bs * QKV;
  qs[t]       = b2f(qrow[t]);
  qs[t + 256] = b2f(qrow[t + 256]);

#pragma unroll
  for (int r = 0; r < 8; ++r) {
    const int n = r * 4 + wv;                 // wave-uniform row
    int im = qkm[s * NKk + n];
    im = im < 0 ? 0 : im;
    const ushort* gsrc = qkv + (size_t)(b * Ss + im) * QKV + 512
                       + ((lane ^ (n & 7)) * 8);
    gload_lds16(gsrc, &Ks[n * 512]);
  }

  int iv = qkm[s * NKk + (lane & 31)];

  __syncthreads();

  // ---- scores + softmax (thread = (h = t>>5, n = t&31)) ----
  const int h = t >> 5;
  const int n = t & 31;
  const bool valid = (iv >= 0);

  float2 a2 = make_float2(0.f, 0.f);
#pragma unroll
  for (int j = 0; j < 8; ++j) {
    const int blk = (h * 8 + j) ^ (n & 7);
    const uint4 kk = *reinterpret_cast<const uint4*>(&Ks[n * 512 + blk * 8]);
    const float* qq = &qs[h * 64 + j * 8];
    a2.x += qq[0] * __uint_as_float(kk.x << 16);
    a2.y += qq[1] * __uint_as_float(kk.x & 0xffff0000u);
    a2.x += qq[2] * __uint_as_float(kk.y << 16);
    a2.y += qq[3] * __uint_as_float(kk.y & 0xffff0000u);
    a2.x += qq[4] * __uint_as_float(kk.z << 16);
    a2.y += qq[5] * __uint_as_float(kk.z & 0xffff0000u);
    a2.x += qq[6] * __uint_as_float(kk.w << 16);
    a2.y += qq[7] * __uint_as_float(kk.w & 0xffff0000u);
  }
  float sc = a2.x + a2.y + rpe[((size_t)bs * NKk + n) * Hh + h];
  sc = valid ? sc * 0.125f : -1e30f;

  float mx = sc;
#pragma unroll
  for (int m = 16; m >= 1; m >>= 1) mx = fmaxf(mx, __shfl_xor(mx, m, 32));
  const float p = valid ? __expf(sc - mx) : 0.f;
  float sum = p;
#pragma unroll
  for (int m = 16; m >= 1; m >>= 1) sum += __shfl_xor(sum, m, 32);
  const float pn = (sum > 0.f) ? (p / sum) : 0.f;

  // ---- ctx elems 2t, 2t+1 ----
  const ushort* vbase = qkv + (size_t)b * Ss * QKV + 1024;
  const int e = 2 * t;
  float c0 = 0.f, c1 = 0.f;
#pragma unroll
  for (int n2 = 0; n2 < 32; ++n2) {
    const int src = (lane & 32) + n2;
    const float a = __shfl(pn, src, 64);
    int row = __shfl(iv, src, 64);
    row = row < 0 ? 0 : row;
    const uint vvu = *reinterpret_cast<const uint*>(
        &vbase[(size_t)row * QKV + (e & 511)]);
    c0 += a * __uint_as_float(vvu << 16);
    c1 += a * __uint_as_float(vvu & 0xffff0000u);
  }
  const uint packed = (uint)f2b(c0) | ((uint)f2b(c1) << 16);
  *reinterpret_cast<uint*>(&ctx[(size_t)bs * 512 + e]) = packed;
}

// ---------------------------------------------------------------------------
// In-place row LayerNorm over DM=512. One wave per row, 4 rows per block.
// ---------------------------------------------------------------------------
__global__ __launch_bounds__(256) void ln_k(
    float* __restrict__ x, const float* __restrict__ g,
    const float* __restrict__ bta)
{
  const int w    = threadIdx.x >> 6;
  const int lane = threadIdx.x & 63;
  const int row  = blockIdx.x * 4 + w;

  float4* xr = reinterpret_cast<float4*>(x + (size_t)row * 512);
  const float4 v0 = xr[lane];
  const float4 v1 = xr[lane + 64];

  float sum = v0.x + v0.y + v0.z + v0.w + v1.x + v1.y + v1.z + v1.w;
  float sq  = v0.x * v0.x + v0.y * v0.y + v0.z * v0.z + v0.w * v0.w
            + v1.x * v1.x + v1.y * v1.y + v1.z * v1.z + v1.w * v1.w;
#pragma unroll
  for (int m = 32; m >= 1; m >>= 1) {
    sum += __shfl_xor(sum, m, 64);
    sq  += __shfl_xor(sq,  m, 64);
  }
  const float mu  = sum * (1.f / 512.f);
  const float var = sq * (1.f / 512.f) - mu * mu;
  const float rs  = rsqrtf(var + 1e-6f);

  const float4 g0 = reinterpret_cast<const float4*>(g)[lane];
  const float4 g1 = reinterpret_cast<const float4*>(g)[lane + 64];
  const float4 b0 = reinterpret_cast<const float4*>(bta)[lane];
  const float4 b1 = reinterpret_cast<const float4*>(bta)[lane + 64];

  float4 o0, o1;
  o0.x = (v0.x - mu) * rs * g0.x + b0.x;
  o0.y = (v0.y - mu) * rs * g0.y + b0.y;
  o0.z = (v0.z - mu) * rs * g0.z + b0.z;
  o0.w = (v0.w - mu) * rs * g0.w + b0.w;
  o1.x = (v1.x - mu) * rs * g1.x + b1.x;
  o1.y = (v1.y - mu) * rs * g1.y + b1.y;
  o1.z = (v1.z - mu) * rs * g1.z + b1.z;
  o1.w = (v1.w - mu) * rs * g1.w + b1.w;
  xr[lane]      = o0;
  xr[lane + 64] = o1;
}

extern "C" void kernel_launch(void* const* d_in, const int* in_sizes, int n_in,
                              void* d_out, int out_size, void* d_ws, size_t ws_size,
                              hipStream_t stream) {
  const float* hs  = (const float*)d_in[0];
  const float* rpe = (const float*)d_in[1];
  const int*   qkm = (const int*)d_in[2];
  const float* wq  = (const float*)d_in[4];
  const float* wk  = (const float*)d_in[5];
  const float* wv  = (const float*)d_in[6];
  const float* fcw = (const float*)d_in[7];
  const float* fcb = (const float*)d_in[8];
  const float* lng = (const float*)d_in[9];
  const float* lnb = (const float*)d_in[10];
  float* out = (float*)d_out;

  // workspace (ushort elems): Xb 2M | Wt3 0.75M | Wtf 0.25M | qkv 6M | cxb 2M
  ushort* Xb  = (ushort*)d_ws;
  ushort* Wt3 = Xb  + (size_t)Mm * DMm;
  ushort* Wtf = Wt3 + (size_t)3 * DMm * DMm;
  ushort* qkv = Wtf + (size_t)DMm * DMm;
  ushort* cxb = qkv + (size_t)Mm * QKV;

  cvt_all_k<<<dim3(8, 8, 8), 256, 0, stream>>>(hs, wq, wk, wv, fcw, Xb, Wt3, Wtf);

  // fused QKV GEMM: 128x96 tiles -> 32x16 = 512 blocks = 2.00/CU
  gemm_pipe<1, 128, 96><<<dim3(Mm / 128, QKV / 96), 256, 0, stream>>>(
      Xb, Wt3, qkv, nullptr, nullptr, QKV);

  attn_k3<<<Mm, 256, 0, stream>>>(qkv, rpe, qkm, cxb);

  // fc GEMM: 128x64 tiles -> 32x8 = 256 blocks = 1.00/CU
  gemm_pipe<0, 128, 64><<<dim3(Mm / 128, DMm / 64), 256, 0, stream>>>(
      cxb, Wtf, out, fcb, hs, DMm);
  ln_k<<<Mm / 4, 256, 0, stream>>>(out, lng, lnb);
}